// Round 1
// baseline (955.741 us; speedup 1.0000x reference)
//
#include <hip/hip_runtime.h>
#include <hip/hip_bf16.h>
#include <stdint.h>

#define S_DIM 2048
#define B_DIM 16
#define H2_DIM 2048
#define V_DIM 1024
#define M_DIM (S_DIM * B_DIM)   // 32768
#define K_HALF 2048
#define K_TOT 4096

typedef __attribute__((ext_vector_type(8))) short s16x8;   // 8 bf16 (4 VGPRs) MFMA frag
typedef __attribute__((ext_vector_type(4))) float f32x4;   // MFMA accumulator

// fp32 -> bf16 round-to-nearest-even
__device__ __forceinline__ uint16_t f2bf(float f) {
    union { float f; uint32_t u; } c; c.f = f;
    uint32_t u = c.u;
    u += 0x7fffu + ((u >> 16) & 1u);
    return (uint16_t)(u >> 16);
}

__device__ __forceinline__ float fast_tanh(float x) {
    // tanh(x) = 1 - 2/(e^{2x}+1); saturates correctly at +/-inf of expf
    float e = __expf(2.0f * x);
    return 1.0f - 2.0f / (e + 1.0f);
}

// async global->LDS, 16B per lane. LDS dest is wave-uniform base + lane*16.
__device__ __forceinline__ void gload_lds16(const void* g, void* l) {
    __builtin_amdgcn_global_load_lds(
        (__attribute__((address_space(1))) void*)(uintptr_t)g,
        (__attribute__((address_space(3))) void*)(uint32_t)(uintptr_t)l,
        16, 0, 0);
}

// ---------------- convert hidden/z fp32 -> bf16 (flat elementwise) ----------------
__global__ void convertA(const float* __restrict__ h, const float* __restrict__ z,
                         uint16_t* __restrict__ a1, uint16_t* __restrict__ a2) {
    const float* src = blockIdx.y ? z : h;
    uint16_t* dst = blockIdx.y ? a2 : a1;
    size_t idx = (size_t)blockIdx.x * blockDim.x + threadIdx.x;  // one uint4 (8 elems) per thread
    const float4* s4 = (const float4*)src;
    float4 a = s4[idx * 2];
    float4 b = s4[idx * 2 + 1];
    uint32_t p0 = f2bf(a.x) | ((uint32_t)f2bf(a.y) << 16);
    uint32_t p1 = f2bf(a.z) | ((uint32_t)f2bf(a.w) << 16);
    uint32_t p2 = f2bf(b.x) | ((uint32_t)f2bf(b.y) << 16);
    uint32_t p3 = f2bf(b.z) | ((uint32_t)f2bf(b.w) << 16);
    ((uint4*)dst)[idx] = make_uint4(p0, p1, p2, p3);
}

// ------------- transpose+convert Ww/Wz [K][V] fp32 -> B^T [V][K] bf16 -------------
__global__ void transposeB(const float* __restrict__ Ww, const float* __restrict__ Wz,
                           uint16_t* __restrict__ B1, uint16_t* __restrict__ B2) {
    __shared__ float tile[32][33];
    const float* src = blockIdx.z ? Wz : Ww;
    uint16_t* dst = blockIdx.z ? B2 : B1;
    int k0 = blockIdx.x * 32, v0 = blockIdx.y * 32;
    int tv = threadIdx.x & 31, tk = threadIdx.x >> 5;  // tk in 0..7
#pragma unroll
    for (int r = 0; r < 4; r++) {
        int k = tk * 4 + r;
        tile[k][tv] = src[(size_t)(k0 + k) * V_DIM + v0 + tv];
    }
    __syncthreads();
#pragma unroll
    for (int r = 0; r < 4; r++) {
        int v = tk * 4 + r;
        dst[(size_t)(v0 + v) * K_HALF + k0 + tv] = f2bf(tile[tv][v]);
    }
}

// ---------------------------------- fused GEMM ----------------------------------
// C[m,n] = A[m,:]·B^T[n,:] over K=4096 (two K=2048 halves), then
// u[m] += sum_n tanh(C[m,n] + bias[n]) * Vw[n]   (atomicAdd partial per N-block)
template <bool PRE>
__global__ __launch_bounds__(256) void gemm_kernel(
    const uint16_t* __restrict__ A1, const uint16_t* __restrict__ A2,
    const float* __restrict__ F1, const float* __restrict__ F2,
    const uint16_t* __restrict__ B1, const uint16_t* __restrict__ B2,
    const float* __restrict__ bw, const float* __restrict__ bz,
    const float* __restrict__ wa_p, const float* __restrict__ Vw,
    float* __restrict__ u) {
    // LDS tiles: [128 rows][8 chunks of 8 bf16], chunk slot XOR-swizzled by (row&7)
    __shared__ __align__(16) uint16_t lA[128 * 64];
    __shared__ __align__(16) uint16_t lB[128 * 64];

    const int tid = threadIdx.x;
    const int lane = tid & 63;
    const int wv = tid >> 6;                    // wave 0..3, 2x2 grid
    const int wm = (wv >> 1) * 64, wn = (wv & 1) * 64;
    const int mBase = blockIdx.y * 128, nBase = blockIdx.x * 128;
    const int lr = lane >> 3;                   // row within 8-row staging group
    const int lc = lane & 7;                    // LDS chunk slot
    const int cg = lc ^ lr;                     // swizzled global chunk
    const int col = lane & 15, quad = lane >> 4;

    f32x4 acc[4][4] = {};

    for (int kb = 0; kb < K_TOT; kb += 64) {
        const int kcol = kb & (K_HALF - 1);
        const uint16_t* Ab = (kb < K_HALF) ? A1 : A2;
        const float* Fb = (kb < K_HALF) ? F1 : F2;
        const uint16_t* Bb = (kb < K_HALF) ? B1 : B2;

        __syncthreads();  // previous compute done before overwriting LDS
#pragma unroll
        for (int j = 0; j < 4; j++) {
            const int rb = wv * 32 + j * 8;  // 8 rows per staging instr per wave
            if constexpr (PRE) {
                const uint16_t* gp = Ab + (size_t)(mBase + rb + lr) * K_HALF + kcol + cg * 8;
                gload_lds16(gp, &lA[rb * 64]);
            } else {
                const float* gp = Fb + (size_t)(mBase + rb + lr) * K_HALF + kcol + cg * 8;
                float4 x = ((const float4*)gp)[0];
                float4 y = ((const float4*)gp)[1];
                uint32_t p0 = f2bf(x.x) | ((uint32_t)f2bf(x.y) << 16);
                uint32_t p1 = f2bf(x.z) | ((uint32_t)f2bf(x.w) << 16);
                uint32_t p2 = f2bf(y.x) | ((uint32_t)f2bf(y.y) << 16);
                uint32_t p3 = f2bf(y.z) | ((uint32_t)f2bf(y.w) << 16);
                *(uint4*)&lA[rb * 64 + lane * 8] = make_uint4(p0, p1, p2, p3);
            }
            const uint16_t* gb = Bb + (size_t)(nBase + rb + lr) * K_HALF + kcol + cg * 8;
            gload_lds16(gb, &lB[rb * 64]);
        }
        __syncthreads();  // drains vmcnt/lgkmcnt (compiler-inserted) then barrier

#pragma unroll
        for (int kk = 0; kk < 2; kk++) {
            s16x8 af[4], bf[4];
            const int cidx = kk * 4 + quad;  // global chunk index this quad needs
#pragma unroll
            for (int i = 0; i < 4; i++) {
                int m = wm + i * 16 + col;
                af[i] = *(const s16x8*)&lA[m * 64 + (cidx ^ (m & 7)) * 8];
                int n = wn + i * 16 + col;
                bf[i] = *(const s16x8*)&lB[n * 64 + (cidx ^ (n & 7)) * 8];
            }
#pragma unroll
            for (int i = 0; i < 4; i++)
#pragma unroll
                for (int j = 0; j < 4; j++)
                    acc[i][j] = __builtin_amdgcn_mfma_f32_16x16x32_bf16(af[i], bf[j], acc[i][j], 0, 0, 0);
        }
    }

    // ---- fused epilogue: bias + tanh + Vw-dot, reduce 64 n-cols -> u[m] ----
    const float wa05 = wa_p[0] * 0.5f;
    float biasv[4], vwv[4];
#pragma unroll
    for (int j = 0; j < 4; j++) {
        int n = nBase + wn + j * 16 + col;
        biasv[j] = bw[n] + bz[n] + wa05;
        vwv[j] = Vw[n];
    }
#pragma unroll
    for (int i = 0; i < 4; i++) {
#pragma unroll
        for (int r = 0; r < 4; r++) {
            float s = 0.f;
#pragma unroll
            for (int j = 0; j < 4; j++) {
                float xv = acc[i][j][r] + biasv[j];
                s += fast_tanh(xv) * vwv[j];
            }
            // reduce across the 16 cols held by this quad-group (D: col=lane&15)
            s += __shfl_xor(s, 8);
            s += __shfl_xor(s, 4);
            s += __shfl_xor(s, 2);
            s += __shfl_xor(s, 1);
            if (col == 0)
                atomicAdd(&u[mBase + wm + i * 16 + quad * 4 + r], s);
        }
    }
}

// ------------------- softmax over S per batch, in-place on u=d_out -------------------
__global__ void softmax_kernel(float* __restrict__ u) {
    const int b = blockIdx.x;
    const int t = threadIdx.x;  // 256 threads, 8 s-values each
    __shared__ float redm[4], reds[4];
    float v[8];
    float mx = -1e30f;
#pragma unroll
    for (int k = 0; k < 8; k++) {
        v[k] = u[(size_t)(t + k * 256) * B_DIM + b];
        mx = fmaxf(mx, v[k]);
    }
#pragma unroll
    for (int off = 32; off >= 1; off >>= 1) mx = fmaxf(mx, __shfl_xor(mx, off));
    if ((t & 63) == 0) redm[t >> 6] = mx;
    __syncthreads();
    mx = fmaxf(fmaxf(redm[0], redm[1]), fmaxf(redm[2], redm[3]));
    float s = 0.f;
#pragma unroll
    for (int k = 0; k < 8; k++) {
        v[k] = __expf(v[k] - mx);
        s += v[k];
    }
#pragma unroll
    for (int off = 32; off >= 1; off >>= 1) s += __shfl_xor(s, off);
    if ((t & 63) == 0) reds[t >> 6] = s;
    __syncthreads();
    s = reds[0] + reds[1] + reds[2] + reds[3];
    float inv = 1.0f / s;
#pragma unroll
    for (int k = 0; k < 8; k++)
        u[(size_t)(t + k * 256) * B_DIM + b] = v[k] * inv;
}

extern "C" void kernel_launch(void* const* d_in, const int* in_sizes, int n_in,
                              void* d_out, int out_size, void* d_ws, size_t ws_size,
                              hipStream_t stream) {
    const float* hidden = (const float*)d_in[0];
    const float* z = (const float*)d_in[1];
    const float* Ww = (const float*)d_in[2];
    const float* bw = (const float*)d_in[3];
    const float* Wz = (const float*)d_in[4];
    const float* bz = (const float*)d_in[5];
    const float* Vw = (const float*)d_in[6];
    // d_in[7] = vb: constant shift over the softmax axis -> no effect, dropped
    const float* wa = (const float*)d_in[8];
    float* out = (float*)d_out;

    char* ws = (char*)d_ws;
    const size_t aBytes = (size_t)M_DIM * K_HALF * 2;  // 128 MiB per A matrix (bf16)
    const size_t bBytes = (size_t)V_DIM * K_HALF * 2;  // 4 MiB per B matrix (bf16)
    const bool pre = ws_size >= 2 * aBytes + 2 * bBytes;

    uint16_t *wsA1 = nullptr, *wsA2 = nullptr, *wsB1, *wsB2;
    if (pre) {
        wsA1 = (uint16_t*)ws;
        wsA2 = (uint16_t*)(ws + aBytes);
        wsB1 = (uint16_t*)(ws + 2 * aBytes);
        wsB2 = (uint16_t*)(ws + 2 * aBytes + bBytes);
    } else {
        wsB1 = (uint16_t*)ws;
        wsB2 = (uint16_t*)(ws + bBytes);
    }

    // u lives in d_out (zero it; GEMM accumulates, softmax finishes in-place)
    hipMemsetAsync(d_out, 0, (size_t)M_DIM * sizeof(float), stream);

    transposeB<<<dim3(K_HALF / 32, V_DIM / 32, 2), 256, 0, stream>>>(Ww, Wz, wsB1, wsB2);

    if (pre) {
        convertA<<<dim3((size_t)M_DIM * K_HALF / 8 / 256, 2), 256, 0, stream>>>(hidden, z, wsA1, wsA2);
        gemm_kernel<true><<<dim3(V_DIM / 128, M_DIM / 128), 256, 0, stream>>>(
            wsA1, wsA2, nullptr, nullptr, wsB1, wsB2, bw, bz, wa, Vw, out);
    } else {
        gemm_kernel<false><<<dim3(V_DIM / 128, M_DIM / 128), 256, 0, stream>>>(
            nullptr, nullptr, hidden, z, wsB1, wsB2, bw, bz, wa, Vw, out);
    }

    softmax_kernel<<<B_DIM, 256, 0, stream>>>(out);
}

// Round 2
// 770.240 us; speedup vs baseline: 1.2408x; 1.2408x over previous
//
#include <hip/hip_runtime.h>
#include <hip/hip_bf16.h>
#include <stdint.h>

#define S_DIM 2048
#define B_DIM 16
#define H2_DIM 2048
#define V_DIM 1024
#define M_DIM (S_DIM * B_DIM)   // 32768
#define K_HALF 2048
#define K_TOT 4096

typedef __attribute__((ext_vector_type(8))) short s16x8;   // 8 bf16 (4 VGPRs) MFMA frag
typedef __attribute__((ext_vector_type(4))) float f32x4;   // MFMA accumulator

// fp32 -> bf16 round-to-nearest-even (scalar, used in transposeB only)
__device__ __forceinline__ uint16_t f2bf(float f) {
    union { float f; uint32_t u; } c; c.f = f;
    uint32_t u = c.u;
    u += 0x7fffu + ((u >> 16) & 1u);
    return (uint16_t)(u >> 16);
}

// pack 2 fp32 -> 2 bf16 (round-to-nearest), 3 VALU ops: 2 adds + 1 v_perm_b32
__device__ __forceinline__ uint32_t pack_bf16_rn(float a, float b) {
    union { float f; uint32_t u; } ca, cb; ca.f = a; cb.f = b;
    uint32_t ua = ca.u + 0x8000u;
    uint32_t ub = cb.u + 0x8000u;
    // dst = [ua>>16 (low half), ub>>16 (high half)]
    return __builtin_amdgcn_perm(ub, ua, 0x07060302u);
}

__device__ __forceinline__ float fast_tanh(float x) {
    float e = __expf(2.0f * x);
    return 1.0f - 2.0f / (e + 1.0f);
}

// async global->LDS, 16B per lane. LDS dest is wave-uniform base + lane*16.
__device__ __forceinline__ void gload_lds16(const void* g, void* l) {
    __builtin_amdgcn_global_load_lds(
        (__attribute__((address_space(1))) void*)(uintptr_t)g,
        (__attribute__((address_space(3))) void*)(uint32_t)(uintptr_t)l,
        16, 0, 0);
}

// ------------- transpose+convert Ww/Wz [K][V] fp32 -> B^T [V][K] bf16 -------------
__global__ void transposeB(const float* __restrict__ Ww, const float* __restrict__ Wz,
                           uint16_t* __restrict__ B1, uint16_t* __restrict__ B2) {
    __shared__ float tile[32][33];
    const float* src = blockIdx.z ? Wz : Ww;
    uint16_t* dst = blockIdx.z ? B2 : B1;
    int k0 = blockIdx.x * 32, v0 = blockIdx.y * 32;
    int tv = threadIdx.x & 31, tk = threadIdx.x >> 5;  // tk in 0..7
#pragma unroll
    for (int r = 0; r < 4; r++) {
        int k = tk * 4 + r;
        tile[k][tv] = src[(size_t)(k0 + k) * V_DIM + v0 + tv];
    }
    __syncthreads();
#pragma unroll
    for (int r = 0; r < 4; r++) {
        int v = tk * 4 + r;
        dst[(size_t)(v0 + v) * K_HALF + k0 + tv] = f2bf(tile[tv][v]);
    }
}

// ---------------------------------- fused GEMM ----------------------------------
// 128(m) x 256(n) tile per block; A is fp32 in global, converted to bf16 during
// LDS staging (pack_bf16_rn); B is pre-transposed bf16 staged via global_load_lds.
// Epilogue: u[m] += sum_n tanh(C[m,n]+bias[n]) * Vw[n]
__global__ __launch_bounds__(256, 2) void gemm_kernel(
    const float* __restrict__ F1, const float* __restrict__ F2,
    const uint16_t* __restrict__ B1, const uint16_t* __restrict__ B2,
    const float* __restrict__ bw, const float* __restrict__ bz,
    const float* __restrict__ wa_p, const float* __restrict__ Vw,
    float* __restrict__ u) {
    // LDS: [rows][8 chunks of 8 bf16], chunk slot XOR-swizzled by (row&7)
    __shared__ __align__(16) uint16_t lA[128 * 64];   // 16 KB
    __shared__ __align__(16) uint16_t lB[256 * 64];   // 32 KB

    const int tid = threadIdx.x;
    const int lane = tid & 63;
    const int wv = tid >> 6;                      // wave 0..3, 2x2 grid
    const int wm = (wv >> 1) * 64, wn = (wv & 1) * 128;
    // XCD swizzle: blocks sharing an A-tile (same m, n=0..3) land on the same
    // XCD (ids congruent mod 8) and are temporally adjacent (spaced 8).
    const int id = blockIdx.x;                    // grid = 1024
    const int nBase = ((id >> 3) & 3) * 256;
    const int mBase = ((id & 7) + ((id >> 5) << 3)) * 128;
    const int lr = lane >> 3;                     // row within 8-row staging group
    const int lc = lane & 7;                      // LDS chunk slot
    const int cg = lc ^ lr;                       // swizzled global chunk
    const int col = lane & 15, quad = lane >> 4;

    f32x4 acc[4][8] = {};

    for (int kb = 0; kb < K_TOT; kb += 64) {
        const int kcol = kb & (K_HALF - 1);
        const float* Fb = (kb < K_HALF) ? F1 : F2;
        const uint16_t* Bb = (kb < K_HALF) ? B1 : B2;

        __syncthreads();  // previous compute done before overwriting LDS

        // B: 256 rows, 64/wave via async DMA (issue first, overlaps A convert)
#pragma unroll
        for (int j = 0; j < 8; j++) {
            const int rb = wv * 64 + j * 8;
            const uint16_t* gb = Bb + (size_t)(nBase + rb + lr) * K_HALF + kcol + cg * 8;
            gload_lds16(gb, &lB[rb * 64]);
        }
        // A: 128 rows, 32/wave — load fp32, convert to bf16, write LDS
#pragma unroll
        for (int j = 0; j < 4; j++) {
            const int rb = wv * 32 + j * 8;
            const float* gp = Fb + (size_t)(mBase + rb + lr) * K_HALF + kcol + cg * 8;
            float4 x = ((const float4*)gp)[0];
            float4 y = ((const float4*)gp)[1];
            uint32_t p0 = pack_bf16_rn(x.x, x.y);
            uint32_t p1 = pack_bf16_rn(x.z, x.w);
            uint32_t p2 = pack_bf16_rn(y.x, y.y);
            uint32_t p3 = pack_bf16_rn(y.z, y.w);
            *(uint4*)&lA[rb * 64 + lane * 8] = make_uint4(p0, p1, p2, p3);
        }
        __syncthreads();  // drains vmcnt (B DMA) + lgkmcnt (A writes)

#pragma unroll
        for (int kk = 0; kk < 2; kk++) {
            s16x8 af[4], bf[8];
            const int cidx = kk * 4 + quad;  // global chunk index this quad needs
#pragma unroll
            for (int i = 0; i < 4; i++) {
                int m = wm + i * 16 + col;
                af[i] = *(const s16x8*)&lA[m * 64 + ((cidx ^ (m & 7)) << 3)];
            }
#pragma unroll
            for (int j = 0; j < 8; j++) {
                int n = wn + j * 16 + col;
                bf[j] = *(const s16x8*)&lB[n * 64 + ((cidx ^ (n & 7)) << 3)];
            }
#pragma unroll
            for (int i = 0; i < 4; i++)
#pragma unroll
                for (int j = 0; j < 8; j++)
                    acc[i][j] = __builtin_amdgcn_mfma_f32_16x16x32_bf16(af[i], bf[j], acc[i][j], 0, 0, 0);
        }
    }

    // ---- fused epilogue: bias + tanh + Vw-dot, reduce 128 n-cols -> u[m] ----
    const float wa05 = wa_p[0] * 0.5f;
    float biasv[8], vwv[8];
#pragma unroll
    for (int j = 0; j < 8; j++) {
        int n = nBase + wn + j * 16 + col;
        biasv[j] = bw[n] + bz[n] + wa05;
        vwv[j] = Vw[n];
    }
#pragma unroll
    for (int i = 0; i < 4; i++) {
#pragma unroll
        for (int r = 0; r < 4; r++) {
            float s = 0.f;
#pragma unroll
            for (int j = 0; j < 8; j++) {
                float xv = acc[i][j][r] + biasv[j];
                s += fast_tanh(xv) * vwv[j];
            }
            // reduce across the 16 cols held by this quad-group (D: col=lane&15)
            s += __shfl_xor(s, 8);
            s += __shfl_xor(s, 4);
            s += __shfl_xor(s, 2);
            s += __shfl_xor(s, 1);
            if (col == 0)
                atomicAdd(&u[mBase + wm + i * 16 + quad * 4 + r], s);
        }
    }
}

// ------------------- softmax over S per batch, in-place on u=d_out -------------------
__global__ void softmax_kernel(float* __restrict__ u) {
    const int b = blockIdx.x;
    const int t = threadIdx.x;  // 256 threads, 8 s-values each
    __shared__ float redm[4], reds[4];
    float v[8];
    float mx = -1e30f;
#pragma unroll
    for (int k = 0; k < 8; k++) {
        v[k] = u[(size_t)(t + k * 256) * B_DIM + b];
        mx = fmaxf(mx, v[k]);
    }
#pragma unroll
    for (int off = 32; off >= 1; off >>= 1) mx = fmaxf(mx, __shfl_xor(mx, off));
    if ((t & 63) == 0) redm[t >> 6] = mx;
    __syncthreads();
    mx = fmaxf(fmaxf(redm[0], redm[1]), fmaxf(redm[2], redm[3]));
    float s = 0.f;
#pragma unroll
    for (int k = 0; k < 8; k++) {
        v[k] = __expf(v[k] - mx);
        s += v[k];
    }
#pragma unroll
    for (int off = 32; off >= 1; off >>= 1) s += __shfl_xor(s, off);
    if ((t & 63) == 0) reds[t >> 6] = s;
    __syncthreads();
    s = reds[0] + reds[1] + reds[2] + reds[3];
    float inv = 1.0f / s;
#pragma unroll
    for (int k = 0; k < 8; k++)
        u[(size_t)(t + k * 256) * B_DIM + b] = v[k] * inv;
}

extern "C" void kernel_launch(void* const* d_in, const int* in_sizes, int n_in,
                              void* d_out, int out_size, void* d_ws, size_t ws_size,
                              hipStream_t stream) {
    const float* hidden = (const float*)d_in[0];
    const float* z = (const float*)d_in[1];
    const float* Ww = (const float*)d_in[2];
    const float* bw = (const float*)d_in[3];
    const float* Wz = (const float*)d_in[4];
    const float* bz = (const float*)d_in[5];
    const float* Vw = (const float*)d_in[6];
    // d_in[7] = vb: constant shift over the softmax axis -> no effect, dropped
    const float* wa = (const float*)d_in[8];
    float* out = (float*)d_out;

    char* ws = (char*)d_ws;
    const size_t bBytes = (size_t)V_DIM * K_HALF * 2;  // 4 MiB per B matrix (bf16)
    uint16_t* wsB1 = (uint16_t*)ws;
    uint16_t* wsB2 = (uint16_t*)(ws + bBytes);

    // u lives in d_out (zero it; GEMM accumulates, softmax finishes in-place)
    hipMemsetAsync(d_out, 0, (size_t)M_DIM * sizeof(float), stream);

    transposeB<<<dim3(K_HALF / 32, V_DIM / 32, 2), 256, 0, stream>>>(Ww, Wz, wsB1, wsB2);

    gemm_kernel<<<dim3((M_DIM / 128) * (V_DIM / 256)), 256, 0, stream>>>(
        hidden, z, wsB1, wsB2, bw, bz, wa, Vw, out);

    softmax_kernel<<<B_DIM, 256, 0, stream>>>(out);
}